// Round 1
// 277.487 us; speedup vs baseline: 1.1609x; 1.1609x over previous
//
#include <hip/hip_runtime.h>
#include <math.h>

#define DIM   2048
#define NREF  30
#define KPAD  32
#define BATCH 16384

typedef __attribute__((ext_vector_type(8))) short short8;
typedef __attribute__((ext_vector_type(4))) float f32x4;

// Workspace float offsets
#define WS_VN   0         // 30*2048 fp32
#define WS_G    61440     // 1024
#define WS_T    62464     // 1024
#define WS_FP1  63488     // bf16 B-frags of W2: [64 kstep][2 ntile][64 lane][8]  (128 KB)
#define WS_FP2  96256     // bf16 B-frags of V^T: [128 ctile][64 lane][8]         (128 KB)
// total 129024 floats ~516 KB

__device__ __forceinline__ unsigned short f2bf(float f) {
    unsigned u = __float_as_uint(f);
    u += 0x7FFF + ((u >> 16) & 1);          // round-to-nearest-even
    return (unsigned short)(u >> 16);
}

// ---- prep: blocks 0..29 normalize rows; blocks 30..929 compute G from raw vec ----
// G[i][j] = (v_i.v_j) * scale_i * scale_j == vn_i . vn_j  (independent of normalize)
__global__ void k_prep(const float* __restrict__ vec, float* __restrict__ vn,
                       float* __restrict__ G) {
    int b = blockIdx.x, t = threadIdx.x;
    __shared__ float wsum[3][4];
    if (b < NREF) {
        const float* v = vec + b * DIM;
        float s = 0.f;
        for (int d = t; d < DIM; d += 256) { float xv = v[d]; s += xv * xv; }
        #pragma unroll
        for (int off = 32; off > 0; off >>= 1) s += __shfl_down(s, off);
        if ((t & 63) == 0) wsum[0][t >> 6] = s;
        __syncthreads();
        float tot = wsum[0][0] + wsum[0][1] + wsum[0][2] + wsum[0][3];
        float scale = 1.f / (sqrtf(tot) + 1e-8f);
        float* o = vn + b * DIM;
        for (int d = t; d < DIM; d += 256) o[d] = v[d] * scale;
    } else {
        int idx = b - NREF;
        int i = idx / NREF, j = idx % NREF;
        const float* a = vec + i * DIM;
        const float* c = vec + j * DIM;
        float sab = 0.f, saa = 0.f, sbb = 0.f;
        for (int d = t; d < DIM; d += 256) {
            float av = a[d], cv = c[d];
            sab += av * cv; saa += av * av; sbb += cv * cv;
        }
        #pragma unroll
        for (int off = 32; off > 0; off >>= 1) {
            sab += __shfl_down(sab, off);
            saa += __shfl_down(saa, off);
            sbb += __shfl_down(sbb, off);
        }
        if ((t & 63) == 0) { wsum[0][t >> 6] = sab; wsum[1][t >> 6] = saa; wsum[2][t >> 6] = sbb; }
        __syncthreads();
        if (t == 0) {
            float tab = wsum[0][0] + wsum[0][1] + wsum[0][2] + wsum[0][3];
            float taa = wsum[1][0] + wsum[1][1] + wsum[1][2] + wsum[1][3];
            float tbb = wsum[2][0] + wsum[2][1] + wsum[2][2] + wsum[2][3];
            G[i * NREF + j] = tab / ((sqrtf(taa) + 1e-8f) * (sqrtf(tbb) + 1e-8f));
        }
    }
}

// ---- T: per-ROW recurrence, G cached in LDS, zero cross-thread deps ----
// T[t][j] = -2 * sum_{t<=m<j} T[t][m]*G[m][j];  T[t][t]=2
__global__ void k_T2(const float* __restrict__ G, float* __restrict__ T) {
    int t = threadIdx.x;  // 64 threads
    __shared__ float Gs[NREF * NREF];
    __shared__ float Ts[NREF][NREF];
    for (int idx = t; idx < NREF * NREF; idx += 64) {
        Gs[idx] = G[idx];
        Ts[idx / NREF][idx % NREF] = 0.f;
    }
    __syncthreads();
    if (t < NREF) {
        Ts[t][t] = 2.f;
        for (int j = t + 1; j < NREF; j++) {
            float val = 0.f;
            for (int mm = t; mm < j; mm++) val += Ts[t][mm] * Gs[mm * NREF + j];
            Ts[t][j] = -2.f * val;
        }
    }
    __syncthreads();
    for (int idx = t; idx < NREF * NREF; idx += 64) T[idx] = Ts[idx / NREF][idx % NREF];
}

// ---- mid: blocks 0..7 -> W2 (in LDS) + pack1; blocks 8..39 -> pack2 ----
__global__ void k_mid(const float* __restrict__ vn, const float* __restrict__ T,
                      unsigned short* __restrict__ fp1, unsigned short* __restrict__ fp2) {
    int b = blockIdx.x, t = threadIdx.x;
    if (b < 8) {
        __shared__ float W2s[256][33];     // pad 33 -> conflict-free transpose read
        int d = b * 256 + t;
        float vr[NREF];
        #pragma unroll
        for (int j = 0; j < NREF; j++) vr[j] = vn[j * DIM + d];
        #pragma unroll
        for (int k = 0; k < KPAD; k++) {
            float acc = 0.f;
            if (k < NREF)
                for (int j = 0; j <= k; j++) acc += vr[j] * T[j * NREF + k];
            W2s[t][k] = acc;
        }
        __syncthreads();
        short8* out = (short8*)fp1;
        #pragma unroll
        for (int u = 0; u < 4; u++) {
            int lf = t * 4 + u;                      // 0..1023 local frags
            int ks_l = lf >> 7, nt = (lf >> 6) & 1, lane = lf & 63;
            int q = lane >> 4, n = lane & 15;
            short8 v;
            #pragma unroll
            for (int j = 0; j < 8; j++)
                v[j] = (short)f2bf(W2s[ks_l * 32 + q * 8 + j][nt * 16 + n]);
            out[((b * 8 + ks_l) * 2 + nt) * 64 + lane] = v;
        }
    } else {
        int g = (b - 8) * 256 + t;                   // 0..8191
        int ct = g >> 6, lane = g & 63;
        int q = lane >> 4, n = lane & 15;
        short8 v;
        #pragma unroll
        for (int j = 0; j < 8; j++) {
            int k = q * 8 + j;
            float f = (k < NREF) ? vn[(size_t)k * DIM + ct * 16 + n] : 0.f;
            v[j] = (short)f2bf(f);
        }
        ((short8*)fp2)[ct * 64 + lane] = v;
    }
}

// ---- fused main: S = x*W2 then y = x + bias - S*V^T, x read ONCE into registers ----
// Block: 16 rows, 4 waves. Wave w owns K/cols [w*512, w*512+512) in BOTH phases,
// so the phase-1 x registers (128 VGPR/lane) are exactly what the phase-2 epilogue
// needs. P (MFMA layout: col=lane&15, row=(lane>>4)*4+reg) is redistributed to the
// x-register layout through a per-wave 16x32 LDS tile (pad 36, parity dbuf).
__global__ __launch_bounds__(256, 2) void k_fused(const float* __restrict__ x,
                                                  const short8* __restrict__ fp1,
                                                  const short8* __restrict__ fp2,
                                                  const float* __restrict__ bias,
                                                  float* __restrict__ y) {
    int tid = threadIdx.x;
    int wave = tid >> 6, lane = tid & 63;
    int m = lane & 15, q = lane >> 4;
    int r0 = blockIdx.x * 16;
    int kb = wave * 512;

    const float* xp = x + (size_t)(r0 + m) * DIM + kb + q * 8;

    // load x strip into registers: 32 x f32x4 = 128 VGPR, all loads issued up front
    f32x4 xr[32];
    #pragma unroll
    for (int ks = 0; ks < 16; ks++) {
        xr[2 * ks]     = *(const f32x4*)(xp + ks * 32);
        xr[2 * ks + 1] = *(const f32x4*)(xp + ks * 32 + 4);
    }

    // ---- phase 1: partial S over this wave's K range ----
    f32x4 acc0 = {0.f, 0.f, 0.f, 0.f};
    f32x4 acc1 = {0.f, 0.f, 0.f, 0.f};
    #pragma unroll
    for (int ks = 0; ks < 16; ks++) {
        f32x4 xa = xr[2 * ks], xb = xr[2 * ks + 1];
        short8 a;
        a[0] = (short)f2bf(xa[0]); a[1] = (short)f2bf(xa[1]);
        a[2] = (short)f2bf(xa[2]); a[3] = (short)f2bf(xa[3]);
        a[4] = (short)f2bf(xb[0]); a[5] = (short)f2bf(xb[1]);
        a[6] = (short)f2bf(xb[2]); a[7] = (short)f2bf(xb[3]);
        int ksg = wave * 16 + ks;
        short8 b0 = fp1[(ksg * 2 + 0) * 64 + lane];
        short8 b1 = fp1[(ksg * 2 + 1) * 64 + lane];
        acc0 = __builtin_amdgcn_mfma_f32_16x16x32_bf16(a, b0, acc0, 0, 0, 0);
        acc1 = __builtin_amdgcn_mfma_f32_16x16x32_bf16(a, b1, acc1, 0, 0, 0);
    }

    // ---- cross-wave K reduction -> S (bf16) in LDS ----
    __shared__ f32x4 red[4][64][2];          // 8 KB
    __shared__ unsigned short Slds[16][32];  // 1 KB
    red[wave][lane][0] = acc0;
    red[wave][lane][1] = acc1;
    __syncthreads();
    if (tid < 64) {
        f32x4 s0 = red[0][tid][0], s1 = red[0][tid][1];
        #pragma unroll
        for (int w = 1; w < 4; w++) { s0 += red[w][tid][0]; s1 += red[w][tid][1]; }
        int mq = tid & 15, qq = tid >> 4;
        #pragma unroll
        for (int reg = 0; reg < 4; reg++) {
            Slds[qq * 4 + reg][mq]      = f2bf(s0[reg]);
            Slds[qq * 4 + reg][16 + mq] = f2bf(s1[reg]);
        }
    }
    __syncthreads();

    // ---- phase 2: y = x + bias - S*V^T over this wave's col range ----
    short8 aS = *(const short8*)&Slds[m][q * 8];
    f32x4 zero = {0.f, 0.f, 0.f, 0.f};
    __shared__ float Pb[4][2][16][36];       // per-wave P tile, pad 36, parity dbuf (18 KB)
    const float* bp = bias + kb + q * 8;
    float* yp0 = y + (size_t)(r0 + m) * DIM + kb + q * 8;

    #pragma unroll
    for (int u = 0; u < 16; u++) {
        int pb = u & 1;
        short8 b0 = fp2[(wave * 32 + 2 * u) * 64 + lane];
        short8 b1 = fp2[(wave * 32 + 2 * u + 1) * 64 + lane];
        f32x4 p0 = __builtin_amdgcn_mfma_f32_16x16x32_bf16(aS, b0, zero, 0, 0, 0);
        f32x4 p1 = __builtin_amdgcn_mfma_f32_16x16x32_bf16(aS, b1, zero, 0, 0, 0);
        // scatter P in MFMA layout ...
        #pragma unroll
        for (int reg = 0; reg < 4; reg++) {
            Pb[wave][pb][q * 4 + reg][m]      = p0[reg];
            Pb[wave][pb][q * 4 + reg][16 + m] = p1[reg];
        }
        asm volatile("s_waitcnt lgkmcnt(0)" ::: "memory");  // wave-private tile: no barrier
        // ... gather P in x-register layout (row m, cols q*8..q*8+7)
        f32x4 pr0 = *(const f32x4*)&Pb[wave][pb][m][q * 8];
        f32x4 pr1 = *(const f32x4*)&Pb[wave][pb][m][q * 8 + 4];
        f32x4 bb0 = *(const f32x4*)(bp + u * 32);
        f32x4 bb1 = *(const f32x4*)(bp + u * 32 + 4);
        f32x4 o0 = xr[2 * u] + bb0 - pr0;
        f32x4 o1 = xr[2 * u + 1] + bb1 - pr1;
        *(f32x4*)(yp0 + u * 32)     = o0;   // 32 B/lane contiguous stores
        *(f32x4*)(yp0 + u * 32 + 4) = o1;
    }
}

extern "C" void kernel_launch(void* const* d_in, const int* in_sizes, int n_in,
                              void* d_out, int out_size, void* d_ws, size_t ws_size,
                              hipStream_t stream) {
    const float* x    = (const float*)d_in[0];
    const float* vec  = (const float*)d_in[1];
    const float* bias = (const float*)d_in[2];
    float* out = (float*)d_out;
    float* ws  = (float*)d_ws;

    float* vn = ws + WS_VN;
    float* G  = ws + WS_G;
    float* T  = ws + WS_T;
    unsigned short* fp1 = (unsigned short*)(ws + WS_FP1);
    unsigned short* fp2 = (unsigned short*)(ws + WS_FP2);

    k_prep<<<NREF + NREF * NREF, 256, 0, stream>>>(vec, vn, G);
    k_T2<<<1, 64, 0, stream>>>(G, T);
    k_mid<<<40, 256, 0, stream>>>(vn, T, fp1, fp2);
    k_fused<<<BATCH / 16, 256, 0, stream>>>(x, (const short8*)fp1, (const short8*)fp2, bias, out);
}